// Round 15
// baseline (358.189 us; speedup 1.0000x reference)
//
#include <hip/hip_runtime.h>
#include <hip/hip_fp16.h>

// Problem constants
#define NN 50000              // num nodes
#define EE 300000             // edges per type
#define ETOT (3 * EE)         // 900000
#define HD 64                 // hidden / feature size
#define RB 256                // rows per bucket
#define NB 196                // ceil(NN / RB)
#define CHUNK 8192            // edges per binning block
#define NBLKT ((EE + CHUNK - 1) / CHUNK)   // 37 blocks per edge type
#define NBT (3 * NBLKT)       // 111 flat blocks
#define NTOT (NB * NBT)       // 21756 (bucket,block) cells
#define GS_VPT ((NTOT + 1023) / 1024)      // 22 values per scan thread
#define MAXB 6144             // LDS meta capacity per bucket (mean 4592, +22 sigma)
#define PROJ_NT64 ((NN + 63) / 64)   // 782 64-node proj tiles
#define PP_GRID (NBT + PROJ_NT64)    // place(111) + proj64(782) fused grid

// H layout: __half2 H[n*64+f] = (channel0, channel1), fp16 storage fp32 math
// meta[pos] = col | (etype<<16) | (q14<<18),  q14 = round(val * 16383)
// hist/gbase layout (R11): TRANSPOSED to [bucket][flat] = bucket*NBT+flat.
// R15: proj0 branch rewritten in the EPILOGUE's proven 64-node shape
// (global float4 weight broadcast + scalar LDS x-reads). R13's 16-node
// global-weight proj failed because 16-node tiles amortize the weight
// stream 4x worse; 64-node tiles match the epilogue PROJ phase that
// measured ~free inside a 51 us kernel. Drops the 32 KB Wl: fused LDS
// 37 -> 17.4 KB; one tile per block (grid NBT+782, all resident).

// ---------------------------------------------------------------------------
// CSR build pass 1: per-block LDS histogram over the 196 row buckets.
// ---------------------------------------------------------------------------
__global__ void __launch_bounds__(256)
hist1_kernel(const int* __restrict__ ei0, const int* __restrict__ ei1,
             const int* __restrict__ ei2, int* __restrict__ hist) {
    __shared__ int lh[NB];
    int t = blockIdx.y;
    const int* ei = (t == 0) ? ei0 : (t == 1) ? ei1 : ei2;
    int tid = threadIdx.x;
    for (int i = tid; i < NB; i += 256) lh[i] = 0;
    __syncthreads();
    int e0 = blockIdx.x * CHUNK;
    for (int it = 0; it < CHUNK / 256; ++it) {
        int e = e0 + it * 256 + tid;
        if (e < EE) atomicAdd(&lh[ei[e] >> 8], 1);   // LDS atomic only
    }
    __syncthreads();
    int flat = t * NBLKT + blockIdx.x;
    for (int i = tid; i < NB; i += 256) hist[i * NBT + flat] = lh[i];
}

// ---------------------------------------------------------------------------
// CSR build pass 2: single-block exclusive scan of NTOT counts in
// bucket-major, block-minor order -> gbase + bbase[NB+1] + rp[NN]=ETOT.
// hist/gbase are [bucket][flat], so hist[s] is the scan order directly.
// Also computes the 24 softmax filter weights (threads 0..7).
// ---------------------------------------------------------------------------
__global__ void __launch_bounds__(1024)
gscan_kernel(const int* __restrict__ hist, int* __restrict__ gbase,
             int* __restrict__ bbase, int* __restrict__ rp,
             const float* __restrict__ lw0, const float* __restrict__ lw1,
             float* __restrict__ filt) {
    __shared__ int wsum[16];
    int tid = threadIdx.x, lane = tid & 63, wv = tid >> 6;
    if (tid < 8) {   // filt[b][l][c][:] = softmax(layerW[l][c][:])
        int b = tid >> 2, l = (tid >> 1) & 1, c = tid & 1;
        const float* lw = (b == 0 ? lw0 : lw1) + l * 6 + c * 3;
        float a0 = lw[0], a1 = lw[1], a2 = lw[2];
        float m  = fmaxf(a0, fmaxf(a1, a2));
        float e0 = expf(a0 - m), e1 = expf(a1 - m), e2 = expf(a2 - m);
        float s  = e0 + e1 + e2;
        float* o = filt + tid * 3;
        o[0] = e0 / s; o[1] = e1 / s; o[2] = e2 / s;
    }
    int s0 = tid * GS_VPT;
    int local = 0;
    for (int j = 0; j < GS_VPT; ++j) {
        int s = s0 + j;
        if (s < NTOT) local += hist[s];
    }
    int x = local;
#pragma unroll
    for (int d = 1; d < 64; d <<= 1) {
        int y = __shfl_up(x, d);
        if (lane >= d) x += y;
    }
    if (lane == 63) wsum[wv] = x;
    __syncthreads();
    if (tid == 0) {
        int s = 0;
        for (int i = 0; i < 16; ++i) { int t = wsum[i]; wsum[i] = s; s += t; }
    }
    __syncthreads();
    int run = x + wsum[wv] - local;   // exclusive prefix entering this thread
    for (int j = 0; j < GS_VPT; ++j) {
        int s = s0 + j;
        if (s < NTOT) {
            gbase[s] = run;
            int bucket = s / NBT;
            if (s - bucket * NBT == 0) bbase[bucket] = run;
            run += hist[s];
        }
    }
    if (tid == 0) { bbase[NB] = ETOT; rp[NN] = ETOT; }
}

// ---------------------------------------------------------------------------
// Fused CSR pass 3 + block-0 projection (64-node epilogue-shape proj).
// ---------------------------------------------------------------------------
__global__ void __launch_bounds__(256)
place_proj_kernel(const int* __restrict__ ei0, const int* __restrict__ ei1,
                  const int* __restrict__ ei2,
                  const float* __restrict__ ev0, const float* __restrict__ ev1,
                  const float* __restrict__ ev2,
                  const int* __restrict__ gbase, uint2* __restrict__ staged,
                  const float* __restrict__ Xin, const float* __restrict__ Ws,
                  __half2* __restrict__ Hh) {
    __shared__ float Xs[64 * 65];        // 16.6 KB (proj64)
    __shared__ int   lbase[NB];          // 784 B (place)
    int tid = threadIdx.x;

    if (blockIdx.x < NBT) {
        // ---------------- place ----------------
        int flat = blockIdx.x;
        int t  = flat / NBLKT;
        int bx = flat - t * NBLKT;
        const int*   ei = (t == 0) ? ei0 : (t == 1) ? ei1 : ei2;
        const float* ev = (t == 0) ? ev0 : (t == 1) ? ev1 : ev2;
        for (int i = tid; i < NB; i += 256) lbase[i] = gbase[i * NBT + flat];
        __syncthreads();
        int e0 = bx * CHUNK;
        for (int it = 0; it < CHUNK / 256; ++it) {
            int e = e0 + it * 256 + tid;
            if (e < EE) {
                int row = ei[e];
                int col = ei[EE + e];
                unsigned int q = (unsigned int)__float2int_rn(ev[e] * 16383.0f);
                unsigned int mw = (unsigned int)col | ((unsigned int)t << 16) | (q << 18);
                int pos = atomicAdd(&lbase[row >> 8], 1);
                staged[pos] = make_uint2(mw, (unsigned int)row);
            }
        }
    } else {
        // ---------------- proj64 (block 0 input projection) ----------------
        // Epilogue-PROJ-phase shape: 64 nodes/tile, global float4 weight
        // broadcast, scalar LDS x reads, one tile per block.
        int tile = blockIdx.x - NBT;
        int n0 = tile * 64;
        // stage X tile (f32, float4 loads; 64-col rows keep float4 intact)
        for (int i = tid * 4; i < 64 * 64; i += 1024) {
            int ln = i >> 6, d = i & 63;
            int n = n0 + ln;
            float4 v = make_float4(0.f, 0.f, 0.f, 0.f);
            if (n < NN) v = *(const float4*)&Xin[n * 64 + d];
            *(float4*)&Xs[ln * 65 + d] = v;
        }
        __syncthreads();
        int oc = (tid & 15) * 4;    // 4 consecutive output columns
        int nq = tid >> 4;          // node group 0..15
        float p0[4][4], p1[4][4];
#pragma unroll
        for (int j = 0; j < 4; ++j)
#pragma unroll
            for (int i = 0; i < 4; ++i) { p0[j][i] = 0.f; p1[j][i] = 0.f; }
        for (int f = 0; f < 64; ++f) {
            float4 w0 = *(const float4*)&Ws[f * 64 + oc];          // ch0
            float4 w1 = *(const float4*)&Ws[4096 + f * 64 + oc];   // ch1
#pragma unroll
            for (int j = 0; j < 4; ++j) {
                float x = Xs[(nq + 16 * j) * 65 + f];
                p0[j][0] += x * w0.x; p0[j][1] += x * w0.y;
                p0[j][2] += x * w0.z; p0[j][3] += x * w0.w;
                p1[j][0] += x * w1.x; p1[j][1] += x * w1.y;
                p1[j][2] += x * w1.z; p1[j][3] += x * w1.w;
            }
        }
#pragma unroll
        for (int j = 0; j < 4; ++j) {
            int n = n0 + nq + 16 * j;
            if (n < NN) {
                float4 o4;
                ((__half2*)&o4)[0] = __floats2half2_rn(p0[j][0], p1[j][0]);
                ((__half2*)&o4)[1] = __floats2half2_rn(p0[j][1], p1[j][1]);
                ((__half2*)&o4)[2] = __floats2half2_rn(p0[j][2], p1[j][2]);
                ((__half2*)&o4)[3] = __floats2half2_rn(p0[j][3], p1[j][3]);
                *(float4*)&Hh[n * HD + oc] = o4;
            }
        }
    }
}

// ---------------------------------------------------------------------------
// CSR build pass 4: one block per bucket.
// ---------------------------------------------------------------------------
__global__ void __launch_bounds__(256)
csr_kernel(const uint2* __restrict__ staged, const int* __restrict__ bbase,
           int* __restrict__ rp, unsigned int* __restrict__ meta) {
    __shared__ int hist[RB];
    __shared__ int lcur[RB];
    __shared__ int wsum[4];
    __shared__ unsigned int metaL[MAXB];   // 24 KB
    int b   = blockIdx.x;
    int tid = threadIdx.x;
    int base = bbase[b];
    int cnt  = bbase[b + 1] - base;
    int row0 = b * RB;

    hist[tid] = 0;
    __syncthreads();
    for (int i = tid; i < cnt; i += 256) {
        uint2 s = staged[base + i];
        atomicAdd(&hist[(int)s.y - row0], 1);
    }
    __syncthreads();
    int lane = tid & 63, wv = tid >> 6;
    int v = hist[tid];
    int x = v;
#pragma unroll
    for (int d = 1; d < 64; d <<= 1) {
        int y = __shfl_up(x, d);
        if (lane >= d) x += y;
    }
    if (lane == 63) wsum[wv] = x;
    __syncthreads();
    if (tid == 0) {
        int s = 0;
        for (int i = 0; i < 4; ++i) { int t = wsum[i]; wsum[i] = s; s += t; }
    }
    __syncthreads();
    int excl = x + wsum[wv] - v;
    lcur[tid] = excl;
    int row = row0 + tid;
    if (row < NN) rp[row] = base + excl;
    __syncthreads();
    for (int i = tid; i < cnt; i += 256) {
        uint2 s = staged[base + i];
        int p = atomicAdd(&lcur[(int)s.y - row0], 1);
        metaL[p] = s.x;
    }
    __syncthreads();
    for (int i = tid; i < cnt; i += 256)
        meta[base + i] = metaL[i];
}

// ---------------------------------------------------------------------------
// Per-edge accumulate helper for spmm.
// ---------------------------------------------------------------------------
__device__ __forceinline__ void edge_acc(unsigned int mm, float4 r,
                                         float F00, float F01, float F02,
                                         float F10, float F11, float F12,
                                         float* accA, float* accB) {
    int   et = (mm >> 16) & 3;
    float q  = (float)(mm >> 18);
    float w0 = q * ((et == 0) ? F00 : (et == 1) ? F01 : F02);
    float w1 = q * ((et == 0) ? F10 : (et == 1) ? F11 : F12);
#pragma unroll
    for (int i = 0; i < 4; ++i) {
        float2 x = __half22float2(((const __half2*)&r)[i]);
        accA[i] += w0 * x.x;
        accB[i] += w1 * x.y;
    }
}

// ---------------------------------------------------------------------------
// CSR SpMM-mix (R12): 24 edges per iteration, guards at k+8/k+16.
// ---------------------------------------------------------------------------
__global__ void __launch_bounds__(256)
spmm_kernel(const float4* __restrict__ Hin4, float4* __restrict__ Hout4,
            const unsigned int* __restrict__ meta, const int* __restrict__ rp,
            const float* __restrict__ filt /* [2][3] for this pass */) {
    const int wid  = threadIdx.x >> 6;
    const int lane = threadIdx.x & 63;
    const int g    = lane >> 4;
    const int fq   = lane & 15;
    const int row  = blockIdx.x * 4 + wid;

    const float s = 1.0f / 16383.0f;
    const float F00 = filt[0] * s, F01 = filt[1] * s, F02 = filt[2] * s;
    const float F10 = filt[3] * s, F11 = filt[4] * s, F12 = filt[5] * s;

    float accA[4] = {0.f, 0.f, 0.f, 0.f};   // ch0
    float accB[4] = {0.f, 0.f, 0.f, 0.f};   // ch1

    const int beg = rp[row], end = rp[row + 1];
    for (int j0 = beg; j0 < end; j0 += 64) {
        int cnt = min(end - j0, 64);
        unsigned int m = (lane < cnt) ? meta[j0 + lane] : 0u;
        for (int k = 0; k < cnt; k += 24) {
            unsigned int mmA = (unsigned int)__shfl((int)m, k + g);
            unsigned int mmB = (unsigned int)__shfl((int)m, k + 4 + g);
            float4 rA = Hin4[(mmA & 0xffffu) * 16 + fq];
            float4 rB = Hin4[(mmB & 0xffffu) * 16 + fq];
            if (k + 16 < cnt) {
                // 24-edge path: 6 gathers in flight, one waitcnt round
                unsigned int mmC = (unsigned int)__shfl((int)m, k + 8 + g);
                unsigned int mmD = (unsigned int)__shfl((int)m, k + 12 + g);
                unsigned int mmE = (unsigned int)__shfl((int)m, k + 16 + g);
                unsigned int mmF = (unsigned int)__shfl((int)m, k + 20 + g);
                float4 rC = Hin4[(mmC & 0xffffu) * 16 + fq];
                float4 rD = Hin4[(mmD & 0xffffu) * 16 + fq];
                float4 rE = Hin4[(mmE & 0xffffu) * 16 + fq];
                float4 rF = Hin4[(mmF & 0xffffu) * 16 + fq];
                edge_acc(mmA, rA, F00, F01, F02, F10, F11, F12, accA, accB);
                edge_acc(mmB, rB, F00, F01, F02, F10, F11, F12, accA, accB);
                edge_acc(mmC, rC, F00, F01, F02, F10, F11, F12, accA, accB);
                edge_acc(mmD, rD, F00, F01, F02, F10, F11, F12, accA, accB);
                edge_acc(mmE, rE, F00, F01, F02, F10, F11, F12, accA, accB);
                edge_acc(mmF, rF, F00, F01, F02, F10, F11, F12, accA, accB);
            } else if (k + 8 < cnt) {
                // 16-edge path
                unsigned int mmC = (unsigned int)__shfl((int)m, k + 8 + g);
                unsigned int mmD = (unsigned int)__shfl((int)m, k + 12 + g);
                float4 rC = Hin4[(mmC & 0xffffu) * 16 + fq];
                float4 rD = Hin4[(mmD & 0xffffu) * 16 + fq];
                edge_acc(mmA, rA, F00, F01, F02, F10, F11, F12, accA, accB);
                edge_acc(mmB, rB, F00, F01, F02, F10, F11, F12, accA, accB);
                edge_acc(mmC, rC, F00, F01, F02, F10, F11, F12, accA, accB);
                edge_acc(mmD, rD, F00, F01, F02, F10, F11, F12, accA, accB);
            } else {
                // 8-edge tail
                edge_acc(mmA, rA, F00, F01, F02, F10, F11, F12, accA, accB);
                edge_acc(mmB, rB, F00, F01, F02, F10, F11, F12, accA, accB);
            }
        }
    }
#pragma unroll
    for (int i = 0; i < 4; ++i) {
        accA[i] += __shfl_xor(accA[i], 16); accA[i] += __shfl_xor(accA[i], 32);
        accB[i] += __shfl_xor(accB[i], 16); accB[i] += __shfl_xor(accB[i], 32);
    }
    if (g == 0) {
        float4 o4;
        ((__half2*)&o4)[0] = __floats2half2_rn(accA[0], accB[0]);
        ((__half2*)&o4)[1] = __floats2half2_rn(accA[1], accB[1]);
        ((__half2*)&o4)[2] = __floats2half2_rn(accA[2], accB[2]);
        ((__half2*)&o4)[3] = __floats2half2_rn(accA[3], accB[3]);
        Hout4[row * 16 + fq] = o4;
    }
}

// ---------------------------------------------------------------------------
// Epilogue (R5-exact — CLOSED at 52 VGPR / ~51 us).
// ---------------------------------------------------------------------------
#define EPI_TILE 64
#define HS_STRIDE 133
template<bool PROJ>
__global__ void __launch_bounds__(256, 4)
epilogue_kernel(const __half2* __restrict__ X0, const __half2* __restrict__ H,
                const float* __restrict__ linW, const float* __restrict__ linb,
                const float* __restrict__ Wsn, float* __restrict__ out,
                __half2* __restrict__ X0out) {
    __shared__ float Hs[EPI_TILE * HS_STRIDE];   // 34.0 KB
    int tid = threadIdx.x;
    int oc = (tid & 15) * 4;    // 4 consecutive output columns
    int nq = tid >> 4;          // node group 0..15
    float bias[4];
#pragma unroll
    for (int i = 0; i < 4; ++i) bias[i] = linb[oc + i];
    const int ntiles = (NN + EPI_TILE - 1) / EPI_TILE;
    for (int tile = blockIdx.x; tile < ntiles; tile += gridDim.x) {
        int n0 = tile * EPI_TILE;
        __syncthreads();
        for (int i = tid; i < EPI_TILE * 64; i += 256) {
            int ln = i >> 6, d = i & 63;
            int n = n0 + ln;
            float2 x0 = make_float2(0.f, 0.f), h = make_float2(0.f, 0.f);
            if (n < NN) {
                x0 = __half22float2(X0[n * HD + d]);
                h  = __half22float2(H [n * HD + d]);
            }
            float z0 = fmaxf(0.5f * x0.x + 0.5f * h.x, 0.f);
            float z1 = fmaxf(0.5f * x0.y + 0.5f * h.y, 0.f);
            Hs[ln * HS_STRIDE + d]      = 0.8f * z0 + 0.2f * x0.x;
            Hs[ln * HS_STRIDE + 64 + d] = 0.8f * z1 + 0.2f * x0.y;
        }
        __syncthreads();
        // ---- GEMM1: acc[j][i] = bias[i] + sum_k Hm[nq+16j][k]*linW[k][oc+i]
        float acc[4][4];
#pragma unroll
        for (int j = 0; j < 4; ++j)
#pragma unroll
            for (int i = 0; i < 4; ++i) acc[j][i] = bias[i];
        for (int k = 0; k < 128; ++k) {
            float4 w4 = *(const float4*)&linW[k * 64 + oc];
#pragma unroll
            for (int j = 0; j < 4; ++j) {
                float x = Hs[(nq + 16 * j) * HS_STRIDE + k];
                acc[j][0] += x * w4.x; acc[j][1] += x * w4.y;
                acc[j][2] += x * w4.z; acc[j][3] += x * w4.w;
            }
        }
        if (!PROJ) {
#pragma unroll
            for (int j = 0; j < 4; ++j) {
                int n = n0 + nq + 16 * j;
                if (n < NN) {
#pragma unroll
                    for (int i = 0; i < 4; ++i)
                        out[n * HD + oc + i] = fmaxf(acc[j][i], 0.f);
                }
            }
        } else {
            // ---- fused next-block projection ----
            __syncthreads();   // all GEMM1 reads of Hs complete
#pragma unroll
            for (int j = 0; j < 4; ++j)
#pragma unroll
                for (int i = 0; i < 4; ++i)
                    Hs[(nq + 16 * j) * HS_STRIDE + oc + i] =
                        fmaxf(acc[j][i], 0.f);           // mid tile, f32, in LDS
            __syncthreads();
            float p0[4][4], p1[4][4];
#pragma unroll
            for (int j = 0; j < 4; ++j)
#pragma unroll
                for (int i = 0; i < 4; ++i) { p0[j][i] = 0.f; p1[j][i] = 0.f; }
            for (int f = 0; f < 64; ++f) {
                float4 w0 = *(const float4*)&Wsn[f * 64 + oc];          // ch0
                float4 w1 = *(const float4*)&Wsn[4096 + f * 64 + oc];   // ch1
#pragma unroll
                for (int j = 0; j < 4; ++j) {
                    float x = Hs[(nq + 16 * j) * HS_STRIDE + f];
                    p0[j][0] += x * w0.x; p0[j][1] += x * w0.y;
                    p0[j][2] += x * w0.z; p0[j][3] += x * w0.w;
                    p1[j][0] += x * w1.x; p1[j][1] += x * w1.y;
                    p1[j][2] += x * w1.z; p1[j][3] += x * w1.w;
                }
            }
#pragma unroll
            for (int j = 0; j < 4; ++j) {
                int n = n0 + nq + 16 * j;
                if (n < NN) {
                    float4 o4;
                    ((__half2*)&o4)[0] = __floats2half2_rn(p0[j][0], p1[j][0]);
                    ((__half2*)&o4)[1] = __floats2half2_rn(p0[j][1], p1[j][1]);
                    ((__half2*)&o4)[2] = __floats2half2_rn(p0[j][2], p1[j][2]);
                    ((__half2*)&o4)[3] = __floats2half2_rn(p0[j][3], p1[j][3]);
                    *(float4*)&X0out[n * HD + oc] = o4;
                }
            }
        }
    }
}

// ---------------------------------------------------------------------------
extern "C" void kernel_launch(void* const* d_in, const int* in_sizes, int n_in,
                              void* d_out, int out_size, void* d_ws, size_t ws_size,
                              hipStream_t stream) {
    const float* X     = (const float*)d_in[0];
    const float* ev0   = (const float*)d_in[1];
    const float* ev1   = (const float*)d_in[2];
    const float* ev2   = (const float*)d_in[3];
    const float* Ws0   = (const float*)d_in[4];
    const float* Ws1   = (const float*)d_in[5];
    const float* lw0   = (const float*)d_in[6];
    const float* lw1   = (const float*)d_in[7];
    const float* linW0 = (const float*)d_in[8];
    const float* linb0 = (const float*)d_in[9];
    const float* linW1 = (const float*)d_in[10];
    const float* linb1 = (const float*)d_in[11];
    const int*   ei0   = (const int*)d_in[12];
    const int*   ei1   = (const int*)d_in[13];
    const int*   ei2   = (const int*)d_in[14];
    float* out = (float*)d_out;

    // Workspace (4-byte units):
    // X0h | Ha | Hb (each NN*HD half2) | staged region (NN*HD f32) |
    // filt(32) | hist(NTOT) | gbase(NTOT) | bbase(NB+1 pad) | rp(NN+1 pad) |
    // meta(ETOT)
    float* ws = (float*)d_ws;
    __half2* X0h = (__half2*)(ws);
    __half2* Ha  = (__half2*)(ws + 1 * NN * HD);
    __half2* Hb  = (__half2*)(ws + 2 * NN * HD);
    uint2*   staged = (uint2*)(ws + 3 * NN * HD);  // dead after csr_kernel
    float*   filt   = ws + 4 * NN * HD;
    int*     hist   = (int*)(filt + 32);
    int*     gbase  = hist + NTOT;
    int*     bbase  = gbase + NTOT;
    int*     rp     = bbase + NB + 4;
    unsigned int* meta = (unsigned int*)(rp + NN + 16);

    // ---- filters + atomic-free binned CSR build; proj0 overlapped ----
    dim3 egrid(NBLKT, 3);
    hist1_kernel<<<egrid, 256, 0, stream>>>(ei0, ei1, ei2, hist);
    gscan_kernel<<<1, 1024, 0, stream>>>(hist, gbase, bbase, rp,
                                         lw0, lw1, filt);
    place_proj_kernel<<<PP_GRID, 256, 0, stream>>>(ei0, ei1, ei2,
                                                   ev0, ev1, ev2,
                                                   gbase, staged,
                                                   X, Ws0, X0h);
    csr_kernel<<<NB, 256, 0, stream>>>(staged, bbase, rp, meta);

    // ---- FastGTN block 0 ----
    spmm_kernel<<<NN / 4, 256, 0, stream>>>((const float4*)X0h, (float4*)Ha,
                                            meta, rp, filt + 0);
    spmm_kernel<<<NN / 4, 256, 0, stream>>>((const float4*)Ha, (float4*)Hb,
                                            meta, rp, filt + 6);
    // epilogue0 + proj1 fused: writes the projected X0h for block 1 directly
    epilogue_kernel<true><<<784, 256, 0, stream>>>(X0h, Hb, linW0, linb0,
                                                   Ws1, nullptr, X0h);

    // ---- FastGTN block 1 ----
    spmm_kernel<<<NN / 4, 256, 0, stream>>>((const float4*)X0h, (float4*)Ha,
                                            meta, rp, filt + 12);
    spmm_kernel<<<NN / 4, 256, 0, stream>>>((const float4*)Ha, (float4*)Hb,
                                            meta, rp, filt + 18);
    epilogue_kernel<false><<<784, 256, 0, stream>>>(X0h, Hb, linW1, linb1,
                                                    Ws1, out, nullptr);
}

// Round 16
// 355.852 us; speedup vs baseline: 1.0066x; 1.0066x over previous
//
#include <hip/hip_runtime.h>
#include <hip/hip_fp16.h>

// Problem constants
#define NN 50000              // num nodes
#define EE 300000             // edges per type
#define ETOT (3 * EE)         // 900000
#define HD 64                 // hidden / feature size
#define RB 256                // rows per bucket
#define NB 196                // ceil(NN / RB)
#define CHUNK 8192            // edges per binning block
#define NBLKT ((EE + CHUNK - 1) / CHUNK)   // 37 blocks per edge type
#define NBT (3 * NBLKT)       // 111 flat blocks
#define NTOT (NB * NBT)       // 21756 (bucket,block) cells
#define GS_VPT ((NTOT + 1023) / 1024)      // 22 values per scan thread
#define MAXB 6144             // LDS meta capacity per bucket (mean 4592, +22 sigma)
#define PROJ_NTILE (NN / 16)  // 3125 16-node tiles
#define PP_GRID (NBT + 512)   // place(111) + proj(512) fused grid

// H layout: __half2 H[n*64+f] = (channel0, channel1), fp16 storage fp32 math
// meta[pos] = col | (etype<<16) | (q14<<18),  q14 = round(val * 16383)
// hist/gbase layout (R11): TRANSPOSED to [bucket][flat] = bucket*NBT+flat.
//
// R16 = byte-exact restoration of the session-best R12/R14 configuration
// (356.0/357.2 us measured). Session map: epilogue closed (~51 us latency
// basin, 6 configs); spmm at one-latency-round-per-row (24-edge guarded);
// CSR chain overlapped (R13/R15 probes flat). Remaining untried lever is
// an MFMA epilogue (fp16): ~40 us upside but cliff + absmax risk.

// ---------------------------------------------------------------------------
// CSR build pass 1: per-block LDS histogram over the 196 row buckets.
// ---------------------------------------------------------------------------
__global__ void __launch_bounds__(256)
hist1_kernel(const int* __restrict__ ei0, const int* __restrict__ ei1,
             const int* __restrict__ ei2, int* __restrict__ hist) {
    __shared__ int lh[NB];
    int t = blockIdx.y;
    const int* ei = (t == 0) ? ei0 : (t == 1) ? ei1 : ei2;
    int tid = threadIdx.x;
    for (int i = tid; i < NB; i += 256) lh[i] = 0;
    __syncthreads();
    int e0 = blockIdx.x * CHUNK;
    for (int it = 0; it < CHUNK / 256; ++it) {
        int e = e0 + it * 256 + tid;
        if (e < EE) atomicAdd(&lh[ei[e] >> 8], 1);   // LDS atomic only
    }
    __syncthreads();
    int flat = t * NBLKT + blockIdx.x;
    for (int i = tid; i < NB; i += 256) hist[i * NBT + flat] = lh[i];
}

// ---------------------------------------------------------------------------
// CSR build pass 2: single-block exclusive scan of NTOT counts in
// bucket-major, block-minor order -> gbase + bbase[NB+1] + rp[NN]=ETOT.
// hist/gbase are [bucket][flat], so hist[s] is the scan order directly.
// Also computes the 24 softmax filter weights (threads 0..7).
// ---------------------------------------------------------------------------
__global__ void __launch_bounds__(1024)
gscan_kernel(const int* __restrict__ hist, int* __restrict__ gbase,
             int* __restrict__ bbase, int* __restrict__ rp,
             const float* __restrict__ lw0, const float* __restrict__ lw1,
             float* __restrict__ filt) {
    __shared__ int wsum[16];
    int tid = threadIdx.x, lane = tid & 63, wv = tid >> 6;
    if (tid < 8) {   // filt[b][l][c][:] = softmax(layerW[l][c][:])
        int b = tid >> 2, l = (tid >> 1) & 1, c = tid & 1;
        const float* lw = (b == 0 ? lw0 : lw1) + l * 6 + c * 3;
        float a0 = lw[0], a1 = lw[1], a2 = lw[2];
        float m  = fmaxf(a0, fmaxf(a1, a2));
        float e0 = expf(a0 - m), e1 = expf(a1 - m), e2 = expf(a2 - m);
        float s  = e0 + e1 + e2;
        float* o = filt + tid * 3;
        o[0] = e0 / s; o[1] = e1 / s; o[2] = e2 / s;
    }
    int s0 = tid * GS_VPT;
    int local = 0;
    for (int j = 0; j < GS_VPT; ++j) {
        int s = s0 + j;
        if (s < NTOT) local += hist[s];
    }
    int x = local;
#pragma unroll
    for (int d = 1; d < 64; d <<= 1) {
        int y = __shfl_up(x, d);
        if (lane >= d) x += y;
    }
    if (lane == 63) wsum[wv] = x;
    __syncthreads();
    if (tid == 0) {
        int s = 0;
        for (int i = 0; i < 16; ++i) { int t = wsum[i]; wsum[i] = s; s += t; }
    }
    __syncthreads();
    int run = x + wsum[wv] - local;   // exclusive prefix entering this thread
    for (int j = 0; j < GS_VPT; ++j) {
        int s = s0 + j;
        if (s < NTOT) {
            gbase[s] = run;
            int bucket = s / NBT;
            if (s - bucket * NBT == 0) bbase[bucket] = run;
            run += hist[s];
        }
    }
    if (tid == 0) { bbase[NB] = ETOT; rp[NN] = ETOT; }
}

// ---------------------------------------------------------------------------
// Fused CSR pass 3 + block-0 projection.
// ---------------------------------------------------------------------------
__global__ void __launch_bounds__(256)
place_proj_kernel(const int* __restrict__ ei0, const int* __restrict__ ei1,
                  const int* __restrict__ ei2,
                  const float* __restrict__ ev0, const float* __restrict__ ev1,
                  const float* __restrict__ ev2,
                  const int* __restrict__ gbase, uint2* __restrict__ staged,
                  const float* __restrict__ Xin, const float* __restrict__ Ws,
                  __half2* __restrict__ Hh) {
    __shared__ float Wl[2 * 64 * 64];    // 32 KB (proj)
    __shared__ float Xs[16 * 65];        // 4.2 KB (proj)
    __shared__ int   lbase[NB];          // 784 B (place)
    int tid = threadIdx.x;

    if (blockIdx.x < NBT) {
        // ---------------- place ----------------
        int flat = blockIdx.x;
        int t  = flat / NBLKT;
        int bx = flat - t * NBLKT;
        const int*   ei = (t == 0) ? ei0 : (t == 1) ? ei1 : ei2;
        const float* ev = (t == 0) ? ev0 : (t == 1) ? ev1 : ev2;
        for (int i = tid; i < NB; i += 256) lbase[i] = gbase[i * NBT + flat];
        __syncthreads();
        int e0 = bx * CHUNK;
        for (int it = 0; it < CHUNK / 256; ++it) {
            int e = e0 + it * 256 + tid;
            if (e < EE) {
                int row = ei[e];
                int col = ei[EE + e];
                unsigned int q = (unsigned int)__float2int_rn(ev[e] * 16383.0f);
                unsigned int mw = (unsigned int)col | ((unsigned int)t << 16) | (q << 18);
                int pos = atomicAdd(&lbase[row >> 8], 1);
                staged[pos] = make_uint2(mw, (unsigned int)row);
            }
        }
    } else {
        // ---------------- proj (block 0) ----------------
        for (int i = tid; i < 2 * 64 * 64; i += 256) Wl[i] = Ws[i];
        int oq = (tid & 15) * 4;    // 4 consecutive outputs
        int ln = tid >> 4;          // node 0..15
        for (int tile = blockIdx.x - NBT; tile < PROJ_NTILE; tile += 512) {
            int n0 = tile * 16;
            __syncthreads();
            for (int i = tid; i < 16 * 64; i += 256)
                Xs[(i >> 6) * 65 + (i & 63)] = Xin[(n0 + (i >> 6)) * 64 + (i & 63)];
            __syncthreads();
            float a0[4] = {0.f, 0.f, 0.f, 0.f};
            float a1[4] = {0.f, 0.f, 0.f, 0.f};
            for (int f = 0; f < 64; ++f) {
                float  x  = Xs[ln * 65 + f];
                float4 w0 = *(const float4*)&Wl[f * 64 + oq];
                float4 w1 = *(const float4*)&Wl[4096 + f * 64 + oq];
                a0[0] += x * w0.x; a0[1] += x * w0.y;
                a0[2] += x * w0.z; a0[3] += x * w0.w;
                a1[0] += x * w1.x; a1[1] += x * w1.y;
                a1[2] += x * w1.z; a1[3] += x * w1.w;
            }
            float4 o4;
            ((__half2*)&o4)[0] = __floats2half2_rn(a0[0], a1[0]);
            ((__half2*)&o4)[1] = __floats2half2_rn(a0[1], a1[1]);
            ((__half2*)&o4)[2] = __floats2half2_rn(a0[2], a1[2]);
            ((__half2*)&o4)[3] = __floats2half2_rn(a0[3], a1[3]);
            *(float4*)&Hh[(n0 + ln) * HD + oq] = o4;
        }
    }
}

// ---------------------------------------------------------------------------
// CSR build pass 4: one block per bucket.
// ---------------------------------------------------------------------------
__global__ void __launch_bounds__(256)
csr_kernel(const uint2* __restrict__ staged, const int* __restrict__ bbase,
           int* __restrict__ rp, unsigned int* __restrict__ meta) {
    __shared__ int hist[RB];
    __shared__ int lcur[RB];
    __shared__ int wsum[4];
    __shared__ unsigned int metaL[MAXB];   // 24 KB
    int b   = blockIdx.x;
    int tid = threadIdx.x;
    int base = bbase[b];
    int cnt  = bbase[b + 1] - base;
    int row0 = b * RB;

    hist[tid] = 0;
    __syncthreads();
    for (int i = tid; i < cnt; i += 256) {
        uint2 s = staged[base + i];
        atomicAdd(&hist[(int)s.y - row0], 1);
    }
    __syncthreads();
    int lane = tid & 63, wv = tid >> 6;
    int v = hist[tid];
    int x = v;
#pragma unroll
    for (int d = 1; d < 64; d <<= 1) {
        int y = __shfl_up(x, d);
        if (lane >= d) x += y;
    }
    if (lane == 63) wsum[wv] = x;
    __syncthreads();
    if (tid == 0) {
        int s = 0;
        for (int i = 0; i < 4; ++i) { int t = wsum[i]; wsum[i] = s; s += t; }
    }
    __syncthreads();
    int excl = x + wsum[wv] - v;
    lcur[tid] = excl;
    int row = row0 + tid;
    if (row < NN) rp[row] = base + excl;
    __syncthreads();
    for (int i = tid; i < cnt; i += 256) {
        uint2 s = staged[base + i];
        int p = atomicAdd(&lcur[(int)s.y - row0], 1);
        metaL[p] = s.x;
    }
    __syncthreads();
    for (int i = tid; i < cnt; i += 256)
        meta[base + i] = metaL[i];
}

// ---------------------------------------------------------------------------
// Per-edge accumulate helper for spmm.
// ---------------------------------------------------------------------------
__device__ __forceinline__ void edge_acc(unsigned int mm, float4 r,
                                         float F00, float F01, float F02,
                                         float F10, float F11, float F12,
                                         float* accA, float* accB) {
    int   et = (mm >> 16) & 3;
    float q  = (float)(mm >> 18);
    float w0 = q * ((et == 0) ? F00 : (et == 1) ? F01 : F02);
    float w1 = q * ((et == 0) ? F10 : (et == 1) ? F11 : F12);
#pragma unroll
    for (int i = 0; i < 4; ++i) {
        float2 x = __half22float2(((const __half2*)&r)[i]);
        accA[i] += w0 * x.x;
        accB[i] += w1 * x.y;
    }
}

// ---------------------------------------------------------------------------
// CSR SpMM-mix (R12): 24 edges per iteration, guards at k+8/k+16
// (wave-uniform cnt). Rows are Poisson(18): one 24-edge round puts all ~6
// gathers in flight before a single waitcnt. Zero-padded slots gather H
// row 0 (L1-hot, weight 0). Max shfl index k+12+g <= 63 — no wrap.
// ---------------------------------------------------------------------------
__global__ void __launch_bounds__(256)
spmm_kernel(const float4* __restrict__ Hin4, float4* __restrict__ Hout4,
            const unsigned int* __restrict__ meta, const int* __restrict__ rp,
            const float* __restrict__ filt /* [2][3] for this pass */) {
    const int wid  = threadIdx.x >> 6;
    const int lane = threadIdx.x & 63;
    const int g    = lane >> 4;
    const int fq   = lane & 15;
    const int row  = blockIdx.x * 4 + wid;

    const float s = 1.0f / 16383.0f;
    const float F00 = filt[0] * s, F01 = filt[1] * s, F02 = filt[2] * s;
    const float F10 = filt[3] * s, F11 = filt[4] * s, F12 = filt[5] * s;

    float accA[4] = {0.f, 0.f, 0.f, 0.f};   // ch0
    float accB[4] = {0.f, 0.f, 0.f, 0.f};   // ch1

    const int beg = rp[row], end = rp[row + 1];
    for (int j0 = beg; j0 < end; j0 += 64) {
        int cnt = min(end - j0, 64);
        unsigned int m = (lane < cnt) ? meta[j0 + lane] : 0u;
        for (int k = 0; k < cnt; k += 24) {
            unsigned int mmA = (unsigned int)__shfl((int)m, k + g);
            unsigned int mmB = (unsigned int)__shfl((int)m, k + 4 + g);
            float4 rA = Hin4[(mmA & 0xffffu) * 16 + fq];
            float4 rB = Hin4[(mmB & 0xffffu) * 16 + fq];
            if (k + 16 < cnt) {
                // 24-edge path: 6 gathers in flight, one waitcnt round
                unsigned int mmC = (unsigned int)__shfl((int)m, k + 8 + g);
                unsigned int mmD = (unsigned int)__shfl((int)m, k + 12 + g);
                unsigned int mmE = (unsigned int)__shfl((int)m, k + 16 + g);
                unsigned int mmF = (unsigned int)__shfl((int)m, k + 20 + g);
                float4 rC = Hin4[(mmC & 0xffffu) * 16 + fq];
                float4 rD = Hin4[(mmD & 0xffffu) * 16 + fq];
                float4 rE = Hin4[(mmE & 0xffffu) * 16 + fq];
                float4 rF = Hin4[(mmF & 0xffffu) * 16 + fq];
                edge_acc(mmA, rA, F00, F01, F02, F10, F11, F12, accA, accB);
                edge_acc(mmB, rB, F00, F01, F02, F10, F11, F12, accA, accB);
                edge_acc(mmC, rC, F00, F01, F02, F10, F11, F12, accA, accB);
                edge_acc(mmD, rD, F00, F01, F02, F10, F11, F12, accA, accB);
                edge_acc(mmE, rE, F00, F01, F02, F10, F11, F12, accA, accB);
                edge_acc(mmF, rF, F00, F01, F02, F10, F11, F12, accA, accB);
            } else if (k + 8 < cnt) {
                // 16-edge path
                unsigned int mmC = (unsigned int)__shfl((int)m, k + 8 + g);
                unsigned int mmD = (unsigned int)__shfl((int)m, k + 12 + g);
                float4 rC = Hin4[(mmC & 0xffffu) * 16 + fq];
                float4 rD = Hin4[(mmD & 0xffffu) * 16 + fq];
                edge_acc(mmA, rA, F00, F01, F02, F10, F11, F12, accA, accB);
                edge_acc(mmB, rB, F00, F01, F02, F10, F11, F12, accA, accB);
                edge_acc(mmC, rC, F00, F01, F02, F10, F11, F12, accA, accB);
                edge_acc(mmD, rD, F00, F01, F02, F10, F11, F12, accA, accB);
            } else {
                // 8-edge tail
                edge_acc(mmA, rA, F00, F01, F02, F10, F11, F12, accA, accB);
                edge_acc(mmB, rB, F00, F01, F02, F10, F11, F12, accA, accB);
            }
        }
    }
#pragma unroll
    for (int i = 0; i < 4; ++i) {
        accA[i] += __shfl_xor(accA[i], 16); accA[i] += __shfl_xor(accA[i], 32);
        accB[i] += __shfl_xor(accB[i], 16); accB[i] += __shfl_xor(accB[i], 32);
    }
    if (g == 0) {
        float4 o4;
        ((__half2*)&o4)[0] = __floats2half2_rn(accA[0], accB[0]);
        ((__half2*)&o4)[1] = __floats2half2_rn(accA[1], accB[1]);
        ((__half2*)&o4)[2] = __floats2half2_rn(accA[2], accB[2]);
        ((__half2*)&o4)[3] = __floats2half2_rn(accA[3], accB[3]);
        Hout4[row * 16 + fq] = o4;
    }
}

// ---------------------------------------------------------------------------
// Epilogue (R5-exact — CLOSED at 52 VGPR / ~51 us; six configs mapped the
// surface, this basin is the minimum).
// ---------------------------------------------------------------------------
#define EPI_TILE 64
#define HS_STRIDE 133
template<bool PROJ>
__global__ void __launch_bounds__(256, 4)
epilogue_kernel(const __half2* __restrict__ X0, const __half2* __restrict__ H,
                const float* __restrict__ linW, const float* __restrict__ linb,
                const float* __restrict__ Wsn, float* __restrict__ out,
                __half2* __restrict__ X0out) {
    __shared__ float Hs[EPI_TILE * HS_STRIDE];   // 34.0 KB
    int tid = threadIdx.x;
    int oc = (tid & 15) * 4;    // 4 consecutive output columns
    int nq = tid >> 4;          // node group 0..15
    float bias[4];
#pragma unroll
    for (int i = 0; i < 4; ++i) bias[i] = linb[oc + i];
    const int ntiles = (NN + EPI_TILE - 1) / EPI_TILE;
    for (int tile = blockIdx.x; tile < ntiles; tile += gridDim.x) {
        int n0 = tile * EPI_TILE;
        __syncthreads();
        for (int i = tid; i < EPI_TILE * 64; i += 256) {
            int ln = i >> 6, d = i & 63;
            int n = n0 + ln;
            float2 x0 = make_float2(0.f, 0.f), h = make_float2(0.f, 0.f);
            if (n < NN) {
                x0 = __half22float2(X0[n * HD + d]);
                h  = __half22float2(H [n * HD + d]);
            }
            float z0 = fmaxf(0.5f * x0.x + 0.5f * h.x, 0.f);
            float z1 = fmaxf(0.5f * x0.y + 0.5f * h.y, 0.f);
            Hs[ln * HS_STRIDE + d]      = 0.8f * z0 + 0.2f * x0.x;
            Hs[ln * HS_STRIDE + 64 + d] = 0.8f * z1 + 0.2f * x0.y;
        }
        __syncthreads();
        // ---- GEMM1: acc[j][i] = bias[i] + sum_k Hm[nq+16j][k]*linW[k][oc+i]
        float acc[4][4];
#pragma unroll
        for (int j = 0; j < 4; ++j)
#pragma unroll
            for (int i = 0; i < 4; ++i) acc[j][i] = bias[i];
        for (int k = 0; k < 128; ++k) {
            float4 w4 = *(const float4*)&linW[k * 64 + oc];
#pragma unroll
            for (int j = 0; j < 4; ++j) {
                float x = Hs[(nq + 16 * j) * HS_STRIDE + k];
                acc[j][0] += x * w4.x; acc[j][1] += x * w4.y;
                acc[j][2] += x * w4.z; acc[j][3] += x * w4.w;
            }
        }
        if (!PROJ) {
#pragma unroll
            for (int j = 0; j < 4; ++j) {
                int n = n0 + nq + 16 * j;
                if (n < NN) {
#pragma unroll
                    for (int i = 0; i < 4; ++i)
                        out[n * HD + oc + i] = fmaxf(acc[j][i], 0.f);
                }
            }
        } else {
            // ---- fused next-block projection ----
            __syncthreads();   // all GEMM1 reads of Hs complete
#pragma unroll
            for (int j = 0; j < 4; ++j)
#pragma unroll
                for (int i = 0; i < 4; ++i)
                    Hs[(nq + 16 * j) * HS_STRIDE + oc + i] =
                        fmaxf(acc[j][i], 0.f);           // mid tile, f32, in LDS
            __syncthreads();
            float p0[4][4], p1[4][4];
#pragma unroll
            for (int j = 0; j < 4; ++j)
#pragma unroll
                for (int i = 0; i < 4; ++i) { p0[j][i] = 0.f; p1[j][i] = 0.f; }
            for (int f = 0; f < 64; ++f) {
                float4 w0 = *(const float4*)&Wsn[f * 64 + oc];          // ch0
                float4 w1 = *(const float4*)&Wsn[4096 + f * 64 + oc];   // ch1
#pragma unroll
                for (int j = 0; j < 4; ++j) {
                    float x = Hs[(nq + 16 * j) * HS_STRIDE + f];
                    p0[j][0] += x * w0.x; p0[j][1] += x * w0.y;
                    p0[j][2] += x * w0.z; p0[j][3] += x * w0.w;
                    p1[j][0] += x * w1.x; p1[j][1] += x * w1.y;
                    p1[j][2] += x * w1.z; p1[j][3] += x * w1.w;
                }
            }
#pragma unroll
            for (int j = 0; j < 4; ++j) {
                int n = n0 + nq + 16 * j;
                if (n < NN) {
                    float4 o4;
                    ((__half2*)&o4)[0] = __floats2half2_rn(p0[j][0], p1[j][0]);
                    ((__half2*)&o4)[1] = __floats2half2_rn(p0[j][1], p1[j][1]);
                    ((__half2*)&o4)[2] = __floats2half2_rn(p0[j][2], p1[j][2]);
                    ((__half2*)&o4)[3] = __floats2half2_rn(p0[j][3], p1[j][3]);
                    *(float4*)&X0out[n * HD + oc] = o4;
                }
            }
        }
    }
}

// ---------------------------------------------------------------------------
extern "C" void kernel_launch(void* const* d_in, const int* in_sizes, int n_in,
                              void* d_out, int out_size, void* d_ws, size_t ws_size,
                              hipStream_t stream) {
    const float* X     = (const float*)d_in[0];
    const float* ev0   = (const float*)d_in[1];
    const float* ev1   = (const float*)d_in[2];
    const float* ev2   = (const float*)d_in[3];
    const float* Ws0   = (const float*)d_in[4];
    const float* Ws1   = (const float*)d_in[5];
    const float* lw0   = (const float*)d_in[6];
    const float* lw1   = (const float*)d_in[7];
    const float* linW0 = (const float*)d_in[8];
    const float* linb0 = (const float*)d_in[9];
    const float* linW1 = (const float*)d_in[10];
    const float* linb1 = (const float*)d_in[11];
    const int*   ei0   = (const int*)d_in[12];
    const int*   ei1   = (const int*)d_in[13];
    const int*   ei2   = (const int*)d_in[14];
    float* out = (float*)d_out;

    // Workspace (4-byte units):
    // X0h | Ha | Hb (each NN*HD half2) | staged region (NN*HD f32) |
    // filt(32) | hist(NTOT) | gbase(NTOT) | bbase(NB+1 pad) | rp(NN+1 pad) |
    // meta(ETOT)
    float* ws = (float*)d_ws;
    __half2* X0h = (__half2*)(ws);
    __half2* Ha  = (__half2*)(ws + 1 * NN * HD);
    __half2* Hb  = (__half2*)(ws + 2 * NN * HD);
    uint2*   staged = (uint2*)(ws + 3 * NN * HD);  // dead after csr_kernel
    float*   filt   = ws + 4 * NN * HD;
    int*     hist   = (int*)(filt + 32);
    int*     gbase  = hist + NTOT;
    int*     bbase  = gbase + NTOT;
    int*     rp     = bbase + NB + 4;
    unsigned int* meta = (unsigned int*)(rp + NN + 16);

    // ---- filters + atomic-free binned CSR build; proj0 overlapped ----
    dim3 egrid(NBLKT, 3);
    hist1_kernel<<<egrid, 256, 0, stream>>>(ei0, ei1, ei2, hist);
    gscan_kernel<<<1, 1024, 0, stream>>>(hist, gbase, bbase, rp,
                                         lw0, lw1, filt);
    place_proj_kernel<<<PP_GRID, 256, 0, stream>>>(ei0, ei1, ei2,
                                                   ev0, ev1, ev2,
                                                   gbase, staged,
                                                   X, Ws0, X0h);
    csr_kernel<<<NB, 256, 0, stream>>>(staged, bbase, rp, meta);

    // ---- FastGTN block 0 ----
    spmm_kernel<<<NN / 4, 256, 0, stream>>>((const float4*)X0h, (float4*)Ha,
                                            meta, rp, filt + 0);
    spmm_kernel<<<NN / 4, 256, 0, stream>>>((const float4*)Ha, (float4*)Hb,
                                            meta, rp, filt + 6);
    // epilogue0 + proj1 fused: writes the projected X0h for block 1 directly
    epilogue_kernel<true><<<784, 256, 0, stream>>>(X0h, Hb, linW0, linb0,
                                                   Ws1, nullptr, X0h);

    // ---- FastGTN block 1 ----
    spmm_kernel<<<NN / 4, 256, 0, stream>>>((const float4*)X0h, (float4*)Ha,
                                            meta, rp, filt + 12);
    spmm_kernel<<<NN / 4, 256, 0, stream>>>((const float4*)Ha, (float4*)Hb,
                                            meta, rp, filt + 18);
    epilogue_kernel<false><<<784, 256, 0, stream>>>(X0h, Hb, linW1, linb1,
                                                    Ws1, out, nullptr);
}